// Round 7
// baseline (81.159 us; speedup 1.0000x reference)
//
#include <hip/hip_runtime.h>
#include <hip/hip_bf16.h>

// SimilarityLayer: out[e,q,w,n,m] = <p[e,w,:,n], q[e,q,:,m]> / (|p||q| + 1e-8)
// E=8 W=5 C=640 N=49 Q=75.
// R7: BOTH operands pre-converted to fragment-ordered bf16 images in ws.
//     gemm = pure {dwordx4 loads + MFMA}, no LDS staging, no in-loop barrier,
//     8 waves x 32-row tiles (2x the TLP of R6), 2-ahead 3-buffer register
//     pipeline (fully unrolled, static indices). 3-tier ws fallback.

#define E_CNT 8
#define W_CNT 5
#define C_CNT 640
#define N_CNT 49
#define Q_CNT 75
#define MROWS 245                    // W*N
#define NC32 20                      // K chunks of 32
#define AFRAG_CH 16384               // per (e,chunk): 16 row-tiles x 64 lanes x 16B
#define AIMG_E (NC32 * AFRAG_CH)     // 327,680 B per e
#define AIMG_SIZE (E_CNT * AIMG_E)   // 2,621,440
#define PN_OFF AIMG_SIZE
#define PN_BYTES (E_CNT * 10 * MROWS * 4)
#define WS1 ((size_t)(PN_OFF + PN_BYTES))            // tier-1 (R6 path)

#define BIMG_EQ 81920                // per (e,q): 20 chunks x 4 fj x 64 lanes x 16B
#define BIMG_OFF WS1
#define BIMG_SIZE (600 * BIMG_EQ)    // 49,152,000
#define QN_OFF (BIMG_OFF + BIMG_SIZE)
#define QN_BYTES (600 * 64 * 4)
#define WS2 ((size_t)(QN_OFF + QN_BYTES))            // tier-2 (full)

typedef __attribute__((ext_vector_type(8))) short bf16x8;
typedef __attribute__((ext_vector_type(4))) float f32x4;

static __device__ __forceinline__ short f2bf(float f) {
    __hip_bfloat16 h = __float2bfloat16(f);
    return *reinterpret_cast<short*>(&h);
}

// ---------------- prep_a: proto -> fragment-ordered bf16 A image + partials --
// A[nw][k=c64*64+kb*8+j] -> chunk c32=c64*2+(kb>>2), lane (kb&3)*16|(nw&15),
// byte ((nw>>4)*64 + lane)*16 + j*2.
__global__ __launch_bounds__(256, 4)
void prep_a_kernel(const float* __restrict__ proto,
                   unsigned char* __restrict__ aimg,
                   float* __restrict__ pn_part)
{
    __shared__ float pns[MROWS];
    const int b = blockIdx.x;            // 80 = e*10 + c64
    const int e = b / 10, c64 = b % 10;
    const float* pbase = proto + (size_t)e * (W_CNT * C_CNT * N_CNT);
    unsigned char* ebase = aimg + (size_t)e * AIMG_E;
    const int t = threadIdx.x;
    if (t < MROWS) pns[t] = 0.f;
    __syncthreads();

    #pragma unroll
    for (int i = 0; i < 8; ++i) {
        const int s = t + i * 256;       // slot = kb*245 + nw, kb in [0,8)
        int nw, kb;
        bf16x8 pk;
        if (s < 8 * MROWS) {
            kb = s / MROWS;
            nw = s - kb * MROWS;
            const int w = nw / N_CNT, n = nw - w * N_CNT;
            const float* g = pbase + ((size_t)(w * C_CNT + c64 * 64 + kb * 8)) * N_CNT + n;
            float ss = 0.f;
            #pragma unroll
            for (int j = 0; j < 8; ++j) {
                const float f = g[(size_t)j * N_CNT];
                ss += f * f;
                pk[j] = f2bf(f);
            }
            atomicAdd(&pns[nw], ss);
        } else {
            const int x = s - 8 * MROWS; // zero-pad rows 245..255
            nw = MROWS + (x >> 3);
            kb = x & 7;
            pk = (bf16x8){0, 0, 0, 0, 0, 0, 0, 0};
        }
        const int c32 = c64 * 2 + (kb >> 2);
        const int ln2 = ((kb & 3) << 4) | (nw & 15);
        *reinterpret_cast<bf16x8*>(
            ebase + (size_t)c32 * AFRAG_CH + (size_t)((nw >> 4) * 64 + ln2) * 16) = pk;
    }
    __syncthreads();
    if (t < MROWS) pn_part[(size_t)(e * 10 + c64) * MROWS + t] = pns[t];
}

// ---------------- prep_b: query -> fragment-ordered bf16 B image + q-norms ---
// One block per (e,q). Wave wv owns k in [wv*160, +160); lane = col (0..63,
// 49 valid). Fragment: chunk c=k>>5, fj=col>>4, lane2=((k>>3)&3)*16|(col&15).
__global__ __launch_bounds__(256, 4)
void prep_b_kernel(const float* __restrict__ query,
                   unsigned char* __restrict__ bimg,
                   float* __restrict__ qn)
{
    __shared__ float qns[64];
    const int b = blockIdx.x;            // 600 = e*75 + q
    const float* __restrict__ qsl = query + (size_t)b * (C_CNT * N_CNT);
    unsigned char* __restrict__ bout = bimg + (size_t)b * BIMG_EQ;
    const int t = threadIdx.x, wv = t >> 6, ln = t & 63;
    if (t < 64) qns[t] = 0.f;
    __syncthreads();

    const bool vc = ln < N_CNT;
    float ssq = 0.f;
    #pragma unroll
    for (int g = 0; g < 20; ++g) {       // 20 groups of 8 k
        const int k0 = wv * 160 + g * 8;
        float v[8];
        #pragma unroll
        for (int j = 0; j < 8; ++j)
            v[j] = vc ? qsl[(size_t)(k0 + j) * N_CNT + ln] : 0.f;
        bf16x8 pk;
        #pragma unroll
        for (int j = 0; j < 8; ++j) { ssq += v[j] * v[j]; pk[j] = f2bf(v[j]); }
        const int c = k0 >> 5, lk = (k0 >> 3) & 3;
        *reinterpret_cast<bf16x8*>(
            bout + c * 4096 + (ln >> 4) * 1024 + ((lk << 4) | (ln & 15)) * 16) = pk;
    }
    atomicAdd(&qns[ln], ssq);
    __syncthreads();
    if (t < 64) qn[(size_t)b * 64 + t] = sqrtf(qns[t]);
}

// ---------------- gemm2: pure frag-load + MFMA, 8 waves x 32-row tiles -------
__global__ __launch_bounds__(512, 4)
void gemm2_kernel(const unsigned char* __restrict__ aimg,
                  const unsigned char* __restrict__ bimg,
                  const float* __restrict__ pn_part,
                  const float* __restrict__ qn,
                  float* __restrict__ out)
{
    __shared__ float pnl[256];
    const int b = blockIdx.x;            // 600
    const int e = b & 7;                 // same e -> same XCD -> A image L2-hot
    const int q = b >> 3;
    const int eq = e * Q_CNT + q;
    const int t = threadIdx.x, wv = t >> 6, ln = t & 63;
    const int lrow = ln & 15, lk = ln >> 4;

    const unsigned char* __restrict__ abase =
        aimg + (size_t)e * AIMG_E + (size_t)((wv * 2) * 64 + ln) * 16;
    const unsigned char* __restrict__ bbase =
        bimg + (size_t)eq * BIMG_EQ + (size_t)ln * 16;

    // p-norms once, before the loop (single barrier in the whole kernel)
    if (t < MROWS) {
        float s = 0.f;
        #pragma unroll
        for (int cc = 0; cc < 10; ++cc)
            s += pn_part[(size_t)(e * 10 + cc) * MROWS + t];
        pnl[t] = sqrtf(s);
    }
    __syncthreads();

    bf16x8 Af[3][2], Bf[3][4];
    f32x4 acc[2][4];
    #pragma unroll
    for (int i = 0; i < 2; ++i)
        #pragma unroll
        for (int j = 0; j < 4; ++j) acc[i][j] = (f32x4){0.f, 0.f, 0.f, 0.f};

#define LOADA(c, s_) do {                                                       \
    _Pragma("unroll")                                                           \
    for (int fi_ = 0; fi_ < 2; ++fi_)                                           \
        Af[s_][fi_] = *reinterpret_cast<const bf16x8*>(                         \
            abase + (size_t)(c) * AFRAG_CH + fi_ * 1024);                       \
} while (0)

#define LOADB(c, s_) do {                                                       \
    _Pragma("unroll")                                                           \
    for (int fj_ = 0; fj_ < 4; ++fj_)                                           \
        Bf[s_][fj_] = *reinterpret_cast<const bf16x8*>(                         \
            bbase + (size_t)(c) * 4096 + fj_ * 1024);                           \
} while (0)

    LOADA(0, 0); LOADB(0, 0);
    LOADA(1, 1); LOADB(1, 1);

    #pragma unroll
    for (int cc = 0; cc < NC32; ++cc) {
        if (cc + 2 < NC32) {             // 2-ahead into buffer (cc+2)%3
            LOADA(cc + 2, (cc + 2) % 3);
            LOADB(cc + 2, (cc + 2) % 3);
        }
        const int s = cc % 3;            // compile-time (fully unrolled)
        #pragma unroll
        for (int fi = 0; fi < 2; ++fi)
            #pragma unroll
            for (int fj = 0; fj < 4; ++fj)
                acc[fi][fj] = __builtin_amdgcn_mfma_f32_16x16x32_bf16(
                    Af[s][fi], Bf[s][fj], acc[fi][fj], 0, 0, 0);
    }

    // ---- epilogue ----
    float nq4[4];
    #pragma unroll
    for (int fj = 0; fj < 4; ++fj)
        nq4[fj] = qn[(size_t)eq * 64 + fj * 16 + lrow];   // pre-sqrt'd

    float* __restrict__ osl = out + (size_t)eq * (W_CNT * N_CNT * N_CNT);
    #pragma unroll
    for (int fi = 0; fi < 2; ++fi) {
        #pragma unroll
        for (int rr = 0; rr < 4; ++rr) {
            const int nw = (wv * 2 + fi) * 16 + lk * 4 + rr;  // D row
            if (nw < MROWS) {
                const float np_ = pnl[nw];
                #pragma unroll
                for (int fj = 0; fj < 4; ++fj) {
                    const int m = fj * 16 + lrow;             // D col
                    if (m < N_CNT) {
                        const float den = np_ * nq4[fj] + 1e-8f;
                        osl[nw * N_CNT + m] = acc[fi][fj][rr] * __builtin_amdgcn_rcpf(den);
                    }
                }
            }
        }
    }
#undef LOADA
#undef LOADB
}

// ---------------- tier-1 gemm (R6 path: A image only) ------------------------
__global__ __launch_bounds__(256, 2)
void gemm_t1_kernel(const float* __restrict__ query,
                    const unsigned char* __restrict__ aimg,
                    const float* __restrict__ pn_part,
                    float* __restrict__ out)
{
    __shared__ float pnl[256];
    const int b = blockIdx.x;
    const int e = b & 7;
    const int q = b >> 3;
    const int t = threadIdx.x;
    const int wv = t >> 6, ln = t & 63;
    const int lrow = ln & 15, lk = ln >> 4;

    const float* __restrict__ qsl = query + (size_t)(e * Q_CNT + q) * (C_CNT * N_CNT);
    const unsigned char* __restrict__ afrag =
        aimg + (size_t)e * AIMG_E + (size_t)((wv * 4) * 64 + ln) * 16;

    int colv[4];
    #pragma unroll
    for (int fj = 0; fj < 4; ++fj) {
        const int c_ = fj * 16 + lrow;
        colv[fj] = (c_ < N_CNT) ? c_ : (N_CNT - 1);
    }
    const int kbase = lk * 8;

    bf16x8 afA[4], afB[4];
    float vbA[4][8], vbB[4][8];
    float ssq[4] = {0.f, 0.f, 0.f, 0.f};
    f32x4 acc[4][4];
    #pragma unroll
    for (int i = 0; i < 4; ++i)
        #pragma unroll
        for (int j = 0; j < 4; ++j) acc[i][j] = (f32x4){0.f, 0.f, 0.f, 0.f};

#define T1_LOADA(c, dst) do {                                                   \
    const unsigned char* ap_ = afrag + (size_t)(c) * AFRAG_CH;                  \
    _Pragma("unroll")                                                           \
    for (int fi_ = 0; fi_ < 4; ++fi_)                                           \
        dst[fi_] = *reinterpret_cast<const bf16x8*>(ap_ + fi_ * 1024);          \
} while (0)

#define T1_LOADB(c, dst) do {                                                   \
    _Pragma("unroll")                                                           \
    for (int fj_ = 0; fj_ < 4; ++fj_) {                                         \
        _Pragma("unroll")                                                       \
        for (int j_ = 0; j_ < 8; ++j_)                                          \
            dst[fj_][j_] = qsl[((c) * 32 + kbase + j_) * N_CNT + colv[fj_]];    \
    }                                                                           \
} while (0)

#define T1_CONVB(src, bfr) do {                                                 \
    _Pragma("unroll")                                                           \
    for (int fj_ = 0; fj_ < 4; ++fj_) {                                         \
        float s8_ = 0.f;                                                        \
        _Pragma("unroll")                                                       \
        for (int j_ = 0; j_ < 8; ++j_) {                                        \
            const float f_ = src[fj_][j_];                                      \
            s8_ += f_ * f_;                                                     \
            bfr[fj_][j_] = f2bf(f_);                                            \
        }                                                                       \
        ssq[fj_] += s8_;                                                        \
    }                                                                           \
} while (0)

#define T1_DOMFMA(af, bfr) do {                                                 \
    _Pragma("unroll")                                                           \
    for (int fi_ = 0; fi_ < 4; ++fi_)                                           \
        _Pragma("unroll")                                                       \
        for (int fj_ = 0; fj_ < 4; ++fj_)                                       \
            acc[fi_][fj_] = __builtin_amdgcn_mfma_f32_16x16x32_bf16(            \
                af[fi_], bfr[fj_], acc[fi_][fj_], 0, 0, 0);                     \
} while (0)

    T1_LOADA(0, afA);
    T1_LOADB(0, vbA);

    for (int cc = 0; cc < NC32; cc += 2) {
        {
            bf16x8 bfr[4];
            T1_CONVB(vbA, bfr);
            T1_LOADA(cc + 1, afB);
            T1_LOADB(cc + 1, vbB);
            T1_DOMFMA(afA, bfr);
        }
        {
            bf16x8 bfr[4];
            T1_CONVB(vbB, bfr);
            if (cc + 2 < NC32) {
                T1_LOADA(cc + 2, afA);
                T1_LOADB(cc + 2, vbA);
            }
            T1_DOMFMA(afB, bfr);
        }
    }

    if (t < MROWS) {
        float s = 0.f;
        #pragma unroll
        for (int cc = 0; cc < 10; ++cc)
            s += pn_part[(size_t)(e * 10 + cc) * MROWS + t];
        pnl[t] = sqrtf(s);
    }
    __syncthreads();

    float nq4[4];
    #pragma unroll
    for (int fj = 0; fj < 4; ++fj) {
        float s = ssq[fj];
        s += __shfl_xor(s, 16);
        s += __shfl_xor(s, 32);
        nq4[fj] = sqrtf(s);
    }

    float* __restrict__ osl = out + (size_t)(e * Q_CNT + q) * (W_CNT * N_CNT * N_CNT);
    #pragma unroll
    for (int fi = 0; fi < 4; ++fi) {
        #pragma unroll
        for (int rr = 0; rr < 4; ++rr) {
            const int nw = wv * 64 + fi * 16 + lk * 4 + rr;
            if (nw < MROWS) {
                const float np_ = pnl[nw];
                #pragma unroll
                for (int fj = 0; fj < 4; ++fj) {
                    const int m = fj * 16 + lrow;
                    if (m < N_CNT) {
                        const float den = np_ * nq4[fj] + 1e-8f;
                        osl[nw * N_CNT + m] = acc[fi][fj][rr] * __builtin_amdgcn_rcpf(den);
                    }
                }
            }
        }
    }
#undef T1_LOADA
#undef T1_LOADB
#undef T1_CONVB
#undef T1_DOMFMA
}

// ---------------- tier-0 fallback (R2 kernel, no ws) -------------------------
struct SMemFB {
    unsigned char A[256 * 128];
    unsigned char B[64 * 128];
    float ns[320];
};

__global__ __launch_bounds__(512, 4)
void sim_fallback_kernel(const float* __restrict__ proto,
                         const float* __restrict__ query,
                         float* __restrict__ out)
{
    __shared__ SMemFB smf;
    const int t = threadIdx.x;
    const int e = blockIdx.x / Q_CNT;
    const int q = blockIdx.x - e * Q_CNT;
    const float* pbase = proto + (size_t)e * (W_CNT * C_CNT * N_CNT);
    const float* qbase = query + ((size_t)e * Q_CNT + q) * (C_CNT * N_CNT);
    unsigned char* lds = (unsigned char*)&smf;
    if (t < 320) smf.ns[t] = 0.f;
    if (t < 208) {
        if (t < 88) *reinterpret_cast<f32x4*>(smf.A + 245 * 128 + t * 16) = (f32x4){0.f,0.f,0.f,0.f};
        else        *reinterpret_cast<f32x4*>(smf.B + 49 * 128 + (t - 88) * 16) = (f32x4){0.f,0.f,0.f,0.f};
    }
    const int nslot5 = (t < 304);
    const float* gp[5];
    int offidx[5];
    #pragma unroll
    for (int i = 0; i < 5; ++i) {
        gp[i] = pbase; offidx[i] = 0;
        if (i < 4 || nslot5) {
            const int s = t + i * 512;
            if (s < 1960) {
                const int kb = s / 245, nw = s - kb * 245;
                const int w = nw / 49, n = nw - w * 49;
                gp[i] = pbase + ((size_t)w * C_CNT + kb * 8) * N_CNT + n;
                offidx[i] = (nw * 128 + ((kb ^ (nw & 7)) << 4)) | (nw << 16);
            } else {
                const int s2 = s - 1960;
                const int kb = s2 / 49, mq = s2 - kb * 49;
                gp[i] = qbase + (size_t)(kb * 8) * N_CNT + mq;
                offidx[i] = (32768 + mq * 128 + ((kb ^ (mq & 7)) << 4)) | ((256 + mq) << 16);
            }
        }
    }
    float v[5][8];
    float ss[5] = {0.f,0.f,0.f,0.f,0.f};
    #pragma unroll
    for (int i = 0; i < 4; ++i)
        #pragma unroll
        for (int j = 0; j < 8; ++j) v[i][j] = gp[i][(size_t)j * N_CNT];
    if (nslot5)
        #pragma unroll
        for (int j = 0; j < 8; ++j) v[4][j] = gp[4][(size_t)j * N_CNT];
    f32x4 acc[2][4];
    #pragma unroll
    for (int i = 0; i < 2; ++i)
        #pragma unroll
        for (int j = 0; j < 4; ++j) acc[i][j] = (f32x4){0.f,0.f,0.f,0.f};
    const int wv = t >> 6, ln = t & 63, lrow = ln & 15, lk = ln >> 4;
    for (int kc = 0; kc < 10; ++kc) {
        #pragma unroll
        for (int i = 0; i < 5; ++i) {
            if (i < 4 || nslot5) {
                bf16x8 pk; float s8 = 0.f;
                #pragma unroll
                for (int j = 0; j < 8; ++j) { const float f = v[i][j]; s8 += f*f; pk[j] = f2bf(f); }
                ss[i] += s8;
                *reinterpret_cast<bf16x8*>(lds + (offidx[i] & 0xFFFF)) = pk;
            }
        }
        __syncthreads();
        if (kc < 9) {
            #pragma unroll
            for (int i = 0; i < 4; ++i) {
                gp[i] += 64 * N_CNT;
                #pragma unroll
                for (int j = 0; j < 8; ++j) v[i][j] = gp[i][(size_t)j * N_CNT];
            }
            if (nslot5) {
                gp[4] += 64 * N_CNT;
                #pragma unroll
                for (int j = 0; j < 8; ++j) v[4][j] = gp[4][(size_t)j * N_CNT];
            }
        }
        #pragma unroll
        for (int ks = 0; ks < 2; ++ks) {
            bf16x8 af[2], bfr[4];
            #pragma unroll
            for (int i = 0; i < 2; ++i) {
                const int row = (wv * 2 + i) * 16 + lrow;
                const int gr = (ks * 4 + lk) ^ (row & 7);
                af[i] = *reinterpret_cast<const bf16x8*>(lds + row * 128 + gr * 16);
            }
            #pragma unroll
            for (int j = 0; j < 4; ++j) {
                const int mq = j * 16 + lrow;
                const int gr = (ks * 4 + lk) ^ (mq & 7);
                bfr[j] = *reinterpret_cast<const bf16x8*>(lds + 32768 + mq * 128 + gr * 16);
            }
            #pragma unroll
            for (int i = 0; i < 2; ++i)
                #pragma unroll
                for (int j = 0; j < 4; ++j)
                    acc[i][j] = __builtin_amdgcn_mfma_f32_16x16x32_bf16(af[i], bfr[j], acc[i][j], 0, 0, 0);
        }
        __syncthreads();
    }
    #pragma unroll
    for (int i = 0; i < 5; ++i)
        if (i < 4 || nslot5) atomicAdd(&smf.ns[offidx[i] >> 16], ss[i]);
    __syncthreads();
    float nq[4];
    #pragma unroll
    for (int j = 0; j < 4; ++j) {
        const int mq = j * 16 + lrow;
        nq[j] = (mq < N_CNT) ? sqrtf(smf.ns[256 + mq]) : 1.f;
    }
    float* obase = out + (size_t)(e * Q_CNT + q) * (W_CNT * N_CNT * N_CNT);
    #pragma unroll
    for (int i = 0; i < 2; ++i) {
        #pragma unroll
        for (int rr = 0; rr < 4; ++rr) {
            const int nw = (wv * 2 + i) * 16 + lk * 4 + rr;
            if (nw < W_CNT * N_CNT) {
                const int w = nw / 49, n = nw - w * 49;
                const float np_ = sqrtf(smf.ns[nw]);
                float* orow = obase + ((size_t)w * N_CNT + n) * N_CNT;
                #pragma unroll
                for (int j = 0; j < 4; ++j) {
                    const int mq = j * 16 + lrow;
                    if (mq < N_CNT) orow[mq] = acc[i][j][rr] / (np_ * nq[j] + 1e-8f);
                }
            }
        }
    }
}

extern "C" void kernel_launch(void* const* d_in, const int* in_sizes, int n_in,
                              void* d_out, int out_size, void* d_ws, size_t ws_size,
                              hipStream_t stream)
{
    const float* proto = (const float*)d_in[0];
    const float* query = (const float*)d_in[1];
    float* out = (float*)d_out;

    if (ws_size < WS1) {
        hipLaunchKernelGGL(sim_fallback_kernel, dim3(E_CNT * Q_CNT), dim3(512), 0, stream,
                           proto, query, out);
        return;
    }

    unsigned char* aimg = (unsigned char*)d_ws;
    float* pn_part = (float*)((unsigned char*)d_ws + PN_OFF);

    hipLaunchKernelGGL(prep_a_kernel, dim3(E_CNT * 10), dim3(256), 0, stream,
                       proto, aimg, pn_part);

    if (ws_size >= WS2) {
        unsigned char* bimg = (unsigned char*)d_ws + BIMG_OFF;
        float* qn = (float*)((unsigned char*)d_ws + QN_OFF);
        hipLaunchKernelGGL(prep_b_kernel, dim3(E_CNT * Q_CNT), dim3(256), 0, stream,
                           query, bimg, qn);
        hipLaunchKernelGGL(gemm2_kernel, dim3(E_CNT * Q_CNT), dim3(512), 0, stream,
                           aimg, bimg, pn_part, qn, out);
    } else {
        hipLaunchKernelGGL(gemm_t1_kernel, dim3(E_CNT * Q_CNT), dim3(256), 0, stream,
                           query, aimg, pn_part, out);
    }
}

// Round 8
// 56.650 us; speedup vs baseline: 1.4326x; 1.4326x over previous
//
#include <hip/hip_runtime.h>
#include <hip/hip_bf16.h>

// SimilarityLayer: out[e,q,w,n,m] = <p[e,w,:,n], q[e,q,:,m]> / (|p||q| + 1e-8)
// E=8 W=5 C=640 N=49 Q=75.
// R8: keep R7's fast gemm2 (pure frag-load + MFMA). Fix prep_b latency:
//     2400 blocks (one per (e,q,k-quarter)) -> 9.4 waves/SIMD, VGPR<=64,
//     explicit 2-deep unit pipeline (8 loads in flight while converting).
//     prep_a merged into the same launch. q-norms as per-quarter partials.

#define E_CNT 8
#define W_CNT 5
#define C_CNT 640
#define N_CNT 49
#define Q_CNT 75
#define MROWS 245                    // W*N
#define NC32 20                      // K chunks of 32
#define AFRAG_CH 16384               // per (e,chunk): 16 row-tiles x 64 lanes x 16B
#define AIMG_E (NC32 * AFRAG_CH)     // 327,680 B per e
#define AIMG_SIZE (E_CNT * AIMG_E)   // 2,621,440
#define PN_OFF AIMG_SIZE
#define PN_BYTES (E_CNT * 10 * MROWS * 4)
#define WS1 ((size_t)(PN_OFF + PN_BYTES))            // tier-1 (A-image only)

#define BIMG_EQ 81920                // per (e,q): 20 chunks x 4 fj x 64 lanes x 16B
#define BIMG_OFF WS1
#define BIMG_SIZE (600 * BIMG_EQ)    // 49,152,000
#define QN_OFF (BIMG_OFF + BIMG_SIZE)
#define QN_BYTES (600 * 256 * 4)     // per (e,q): 4 quarters x 64 cols
#define WS2 ((size_t)(QN_OFF + QN_BYTES))            // tier-2 (full)

typedef __attribute__((ext_vector_type(8))) short bf16x8;
typedef __attribute__((ext_vector_type(4))) float f32x4;

static __device__ __forceinline__ short f2bf(float f) {
    __hip_bfloat16 h = __float2bfloat16(f);
    return *reinterpret_cast<short*>(&h);
}

// ---------------- combined prep: B-transpose (blocks 0..2399) + A (2400..2479)
__global__ __launch_bounds__(256, 8)
void prep_combined_kernel(const float* __restrict__ proto,
                          const float* __restrict__ query,
                          unsigned char* __restrict__ aimg,
                          float* __restrict__ pn_part,
                          unsigned char* __restrict__ bimg,
                          float* __restrict__ qn_part)
{
    __shared__ float shm[256];
    const int b = blockIdx.x;
    const int t = threadIdx.x;

    if (b < 2400) {
        // ---- B role: one (e,q) k-quarter (160 k) -> fragment image ----
        const int eq = b >> 2, quarter = b & 3;
        const float* __restrict__ qsl = query + (size_t)eq * (C_CNT * N_CNT);
        unsigned char* __restrict__ bout = bimg + (size_t)eq * BIMG_EQ;
        const int col = t & 63;
        const int ce = (col < N_CNT) ? col : (N_CNT - 1);  // clamp; cols>=49 don't-care
        const int kg0 = t >> 6;            // wave id = first k-group
        if (t < 64) shm[t] = 0.f;
        __syncthreads();

        float ssq = 0.f;
        float v[2][8];
        // unit i (i=0..4): k0 = quarter*160 + (kg0 + 4i)*8
        const float* __restrict__ base0 =
            qsl + (size_t)(quarter * 160 + kg0 * 8) * N_CNT + ce;

#define PB_LOAD(i, buf) do {                                                    \
        const float* p_ = base0 + (size_t)(i) * 32 * N_CNT;                     \
        _Pragma("unroll")                                                       \
        for (int j_ = 0; j_ < 8; ++j_) v[buf][j_] = p_[j_ * N_CNT];             \
    } while (0)

#define PB_PROC(i, buf) do {                                                    \
        bf16x8 pk_;                                                             \
        _Pragma("unroll")                                                       \
        for (int j_ = 0; j_ < 8; ++j_) {                                        \
            const float f_ = v[buf][j_]; ssq += f_ * f_; pk_[j_] = f2bf(f_);    \
        }                                                                       \
        const int k0_ = quarter * 160 + (kg0 + 4 * (i)) * 8;                    \
        const int c_ = k0_ >> 5, lk_ = (k0_ >> 3) & 3;                          \
        *reinterpret_cast<bf16x8*>(bout + c_ * 4096 + (col >> 4) * 1024 +       \
                                   (((lk_ << 4) | (col & 15)) << 4)) = pk_;     \
    } while (0)

        PB_LOAD(0, 0);
        PB_LOAD(1, 1);
        PB_PROC(0, 0);
        PB_LOAD(2, 0);
        PB_PROC(1, 1);
        PB_LOAD(3, 1);
        PB_PROC(2, 0);
        PB_LOAD(4, 0);
        PB_PROC(3, 1);
        PB_PROC(4, 0);
#undef PB_LOAD
#undef PB_PROC

        atomicAdd(&shm[col], ssq);         // 4 threads per col
        __syncthreads();
        if (t < 64) qn_part[(size_t)eq * 256 + quarter * 64 + t] = shm[t];
    } else {
        // ---- A role: proto -> fragment-ordered bf16 A image + partial norms --
        const int b2 = b - 2400;           // 80 = e*10 + c64
        const int e = b2 / 10, c64 = b2 % 10;
        const float* pbase = proto + (size_t)e * (W_CNT * C_CNT * N_CNT);
        unsigned char* ebase = aimg + (size_t)e * AIMG_E;
        if (t < MROWS) shm[t] = 0.f;
        __syncthreads();

        #pragma unroll
        for (int i = 0; i < 8; ++i) {
            const int s = t + i * 256;     // slot = kb*245 + nw, kb in [0,8)
            int nw, kb;
            bf16x8 pk;
            if (s < 8 * MROWS) {
                kb = s / MROWS;
                nw = s - kb * MROWS;
                const int w = nw / N_CNT, n = nw - w * N_CNT;
                const float* g = pbase + ((size_t)(w * C_CNT + c64 * 64 + kb * 8)) * N_CNT + n;
                float ss = 0.f;
                #pragma unroll
                for (int j = 0; j < 8; ++j) {
                    const float f = g[(size_t)j * N_CNT];
                    ss += f * f;
                    pk[j] = f2bf(f);
                }
                atomicAdd(&shm[nw], ss);
            } else {
                const int x = s - 8 * MROWS;   // zero-pad rows 245..255
                nw = MROWS + (x >> 3);
                kb = x & 7;
                pk = (bf16x8){0, 0, 0, 0, 0, 0, 0, 0};
            }
            const int c32 = c64 * 2 + (kb >> 2);
            const int ln2 = ((kb & 3) << 4) | (nw & 15);
            *reinterpret_cast<bf16x8*>(
                ebase + (size_t)c32 * AFRAG_CH + (size_t)((nw >> 4) * 64 + ln2) * 16) = pk;
        }
        __syncthreads();
        if (t < MROWS) pn_part[(size_t)(e * 10 + c64) * MROWS + t] = shm[t];
    }
}

// ---------------- gemm2: pure frag-load + MFMA, 8 waves x 32-row tiles -------
__global__ __launch_bounds__(512, 4)
void gemm2_kernel(const unsigned char* __restrict__ aimg,
                  const unsigned char* __restrict__ bimg,
                  const float* __restrict__ pn_part,
                  const float* __restrict__ qn_part,
                  float* __restrict__ out)
{
    __shared__ float pnl[256];
    const int b = blockIdx.x;            // 600
    const int e = b & 7;                 // same e -> same XCD -> A image L2-hot
    const int q = b >> 3;
    const int eq = e * Q_CNT + q;
    const int t = threadIdx.x, wv = t >> 6, ln = t & 63;
    const int lrow = ln & 15, lk = ln >> 4;

    const unsigned char* __restrict__ abase =
        aimg + (size_t)e * AIMG_E + (size_t)((wv * 2) * 64 + ln) * 16;
    const unsigned char* __restrict__ bbase =
        bimg + (size_t)eq * BIMG_EQ + (size_t)ln * 16;

    // p-norms once, before the loop (single barrier in the whole kernel)
    if (t < MROWS) {
        float s = 0.f;
        #pragma unroll
        for (int cc = 0; cc < 10; ++cc)
            s += pn_part[(size_t)(e * 10 + cc) * MROWS + t];
        pnl[t] = sqrtf(s);
    }
    __syncthreads();

    bf16x8 Af[3][2], Bf[3][4];
    f32x4 acc[2][4];
    #pragma unroll
    for (int i = 0; i < 2; ++i)
        #pragma unroll
        for (int j = 0; j < 4; ++j) acc[i][j] = (f32x4){0.f, 0.f, 0.f, 0.f};

#define LOADA(c, s_) do {                                                       \
    _Pragma("unroll")                                                           \
    for (int fi_ = 0; fi_ < 2; ++fi_)                                           \
        Af[s_][fi_] = *reinterpret_cast<const bf16x8*>(                         \
            abase + (size_t)(c) * AFRAG_CH + fi_ * 1024);                       \
} while (0)

#define LOADB(c, s_) do {                                                       \
    _Pragma("unroll")                                                           \
    for (int fj_ = 0; fj_ < 4; ++fj_)                                           \
        Bf[s_][fj_] = *reinterpret_cast<const bf16x8*>(                         \
            bbase + (size_t)(c) * 4096 + fj_ * 1024);                           \
} while (0)

    LOADA(0, 0); LOADB(0, 0);
    LOADA(1, 1); LOADB(1, 1);

    #pragma unroll
    for (int cc = 0; cc < NC32; ++cc) {
        if (cc + 2 < NC32) {             // 2-ahead into buffer (cc+2)%3
            LOADA(cc + 2, (cc + 2) % 3);
            LOADB(cc + 2, (cc + 2) % 3);
        }
        const int s = cc % 3;            // compile-time (fully unrolled)
        #pragma unroll
        for (int fi = 0; fi < 2; ++fi)
            #pragma unroll
            for (int fj = 0; fj < 4; ++fj)
                acc[fi][fj] = __builtin_amdgcn_mfma_f32_16x16x32_bf16(
                    Af[s][fi], Bf[s][fj], acc[fi][fj], 0, 0, 0);
    }

    // ---- epilogue ----
    const float* __restrict__ qnp = qn_part + (size_t)eq * 256;
    float nq4[4];
    #pragma unroll
    for (int fj = 0; fj < 4; ++fj) {
        const int m = fj * 16 + lrow;
        nq4[fj] = sqrtf(qnp[m] + qnp[64 + m] + qnp[128 + m] + qnp[192 + m]);
    }

    float* __restrict__ osl = out + (size_t)eq * (W_CNT * N_CNT * N_CNT);
    #pragma unroll
    for (int fi = 0; fi < 2; ++fi) {
        #pragma unroll
        for (int rr = 0; rr < 4; ++rr) {
            const int nw = (wv * 2 + fi) * 16 + lk * 4 + rr;  // D row
            if (nw < MROWS) {
                const float np_ = pnl[nw];
                #pragma unroll
                for (int fj = 0; fj < 4; ++fj) {
                    const int m = fj * 16 + lrow;             // D col
                    if (m < N_CNT) {
                        const float den = np_ * nq4[fj] + 1e-8f;
                        osl[nw * N_CNT + m] = acc[fi][fj][rr] * __builtin_amdgcn_rcpf(den);
                    }
                }
            }
        }
    }
#undef LOADA
#undef LOADB
}

// ---------------- tier-1: prep_a standalone + gemm_t1 (R6 path) --------------
__global__ __launch_bounds__(256, 4)
void prep_a_kernel(const float* __restrict__ proto,
                   unsigned char* __restrict__ aimg,
                   float* __restrict__ pn_part)
{
    __shared__ float pns[MROWS];
    const int b = blockIdx.x;            // 80 = e*10 + c64
    const int e = b / 10, c64 = b % 10;
    const float* pbase = proto + (size_t)e * (W_CNT * C_CNT * N_CNT);
    unsigned char* ebase = aimg + (size_t)e * AIMG_E;
    const int t = threadIdx.x;
    if (t < MROWS) pns[t] = 0.f;
    __syncthreads();

    #pragma unroll
    for (int i = 0; i < 8; ++i) {
        const int s = t + i * 256;
        int nw, kb;
        bf16x8 pk;
        if (s < 8 * MROWS) {
            kb = s / MROWS;
            nw = s - kb * MROWS;
            const int w = nw / N_CNT, n = nw - w * N_CNT;
            const float* g = pbase + ((size_t)(w * C_CNT + c64 * 64 + kb * 8)) * N_CNT + n;
            float ss = 0.f;
            #pragma unroll
            for (int j = 0; j < 8; ++j) {
                const float f = g[(size_t)j * N_CNT];
                ss += f * f;
                pk[j] = f2bf(f);
            }
            atomicAdd(&pns[nw], ss);
        } else {
            const int x = s - 8 * MROWS;
            nw = MROWS + (x >> 3);
            kb = x & 7;
            pk = (bf16x8){0, 0, 0, 0, 0, 0, 0, 0};
        }
        const int c32 = c64 * 2 + (kb >> 2);
        const int ln2 = ((kb & 3) << 4) | (nw & 15);
        *reinterpret_cast<bf16x8*>(
            ebase + (size_t)c32 * AFRAG_CH + (size_t)((nw >> 4) * 64 + ln2) * 16) = pk;
    }
    __syncthreads();
    if (t < MROWS) pn_part[(size_t)(e * 10 + c64) * MROWS + t] = pns[t];
}

__global__ __launch_bounds__(256, 2)
void gemm_t1_kernel(const float* __restrict__ query,
                    const unsigned char* __restrict__ aimg,
                    const float* __restrict__ pn_part,
                    float* __restrict__ out)
{
    __shared__ float pnl[256];
    const int b = blockIdx.x;
    const int e = b & 7;
    const int q = b >> 3;
    const int t = threadIdx.x;
    const int wv = t >> 6, ln = t & 63;
    const int lrow = ln & 15, lk = ln >> 4;

    const float* __restrict__ qsl = query + (size_t)(e * Q_CNT + q) * (C_CNT * N_CNT);
    const unsigned char* __restrict__ afrag =
        aimg + (size_t)e * AIMG_E + (size_t)((wv * 4) * 64 + ln) * 16;

    int colv[4];
    #pragma unroll
    for (int fj = 0; fj < 4; ++fj) {
        const int c_ = fj * 16 + lrow;
        colv[fj] = (c_ < N_CNT) ? c_ : (N_CNT - 1);
    }
    const int kbase = lk * 8;

    bf16x8 afA[4], afB[4];
    float vbA[4][8], vbB[4][8];
    float ssq[4] = {0.f, 0.f, 0.f, 0.f};
    f32x4 acc[4][4];
    #pragma unroll
    for (int i = 0; i < 4; ++i)
        #pragma unroll
        for (int j = 0; j < 4; ++j) acc[i][j] = (f32x4){0.f, 0.f, 0.f, 0.f};

#define T1_LOADA(c, dst) do {                                                   \
    const unsigned char* ap_ = afrag + (size_t)(c) * AFRAG_CH;                  \
    _Pragma("unroll")                                                           \
    for (int fi_ = 0; fi_ < 4; ++fi_)                                           \
        dst[fi_] = *reinterpret_cast<const bf16x8*>(ap_ + fi_ * 1024);          \
} while (0)

#define T1_LOADB(c, dst) do {                                                   \
    _Pragma("unroll")                                                           \
    for (int fj_ = 0; fj_ < 4; ++fj_) {                                         \
        _Pragma("unroll")                                                       \
        for (int j_ = 0; j_ < 8; ++j_)                                          \
            dst[fj_][j_] = qsl[((c) * 32 + kbase + j_) * N_CNT + colv[fj_]];    \
    }                                                                           \
} while (0)

#define T1_CONVB(src, bfr) do {                                                 \
    _Pragma("unroll")                                                           \
    for (int fj_ = 0; fj_ < 4; ++fj_) {                                         \
        float s8_ = 0.f;                                                        \
        _Pragma("unroll")                                                       \
        for (int j_ = 0; j_ < 8; ++j_) {                                        \
            const float f_ = src[fj_][j_];                                      \
            s8_ += f_ * f_;                                                     \
            bfr[fj_][j_] = f2bf(f_);                                            \
        }                                                                       \
        ssq[fj_] += s8_;                                                        \
    }                                                                           \
} while (0)

#define T1_DOMFMA(af, bfr) do {                                                 \
    _Pragma("unroll")                                                           \
    for (int fi_ = 0; fi_ < 4; ++fi_)                                           \
        _Pragma("unroll")                                                       \
        for (int fj_ = 0; fj_ < 4; ++fj_)                                       \
            acc[fi_][fj_] = __builtin_amdgcn_mfma_f32_16x16x32_bf16(            \
                af[fi_], bfr[fj_], acc[fi_][fj_], 0, 0, 0);                     \
} while (0)

    T1_LOADA(0, afA);
    T1_LOADB(0, vbA);

    for (int cc = 0; cc < NC32; cc += 2) {
        {
            bf16x8 bfr[4];
            T1_CONVB(vbA, bfr);
            T1_LOADA(cc + 1, afB);
            T1_LOADB(cc + 1, vbB);
            T1_DOMFMA(afA, bfr);
        }
        {
            bf16x8 bfr[4];
            T1_CONVB(vbB, bfr);
            if (cc + 2 < NC32) {
                T1_LOADA(cc + 2, afA);
                T1_LOADB(cc + 2, vbA);
            }
            T1_DOMFMA(afB, bfr);
        }
    }

    if (t < MROWS) {
        float s = 0.f;
        #pragma unroll
        for (int cc = 0; cc < 10; ++cc)
            s += pn_part[(size_t)(e * 10 + cc) * MROWS + t];
        pnl[t] = sqrtf(s);
    }
    __syncthreads();

    float nq4[4];
    #pragma unroll
    for (int fj = 0; fj < 4; ++fj) {
        float s = ssq[fj];
        s += __shfl_xor(s, 16);
        s += __shfl_xor(s, 32);
        nq4[fj] = sqrtf(s);
    }

    float* __restrict__ osl = out + (size_t)(e * Q_CNT + q) * (W_CNT * N_CNT * N_CNT);
    #pragma unroll
    for (int fi = 0; fi < 4; ++fi) {
        #pragma unroll
        for (int rr = 0; rr < 4; ++rr) {
            const int nw = wv * 64 + fi * 16 + lk * 4 + rr;
            if (nw < MROWS) {
                const float np_ = pnl[nw];
                #pragma unroll
                for (int fj = 0; fj < 4; ++fj) {
                    const int m = fj * 16 + lrow;
                    if (m < N_CNT) {
                        const float den = np_ * nq4[fj] + 1e-8f;
                        osl[nw * N_CNT + m] = acc[fi][fj][rr] * __builtin_amdgcn_rcpf(den);
                    }
                }
            }
        }
    }
#undef T1_LOADA
#undef T1_LOADB
#undef T1_CONVB
#undef T1_DOMFMA
}

// ---------------- tier-0 fallback (R2 kernel, no ws) -------------------------
struct SMemFB {
    unsigned char A[256 * 128];
    unsigned char B[64 * 128];
    float ns[320];
};

__global__ __launch_bounds__(512, 4)
void sim_fallback_kernel(const float* __restrict__ proto,
                         const float* __restrict__ query,
                         float* __restrict__ out)
{
    __shared__ SMemFB smf;
    const int t = threadIdx.x;
    const int e = blockIdx.x / Q_CNT;
    const int q = blockIdx.x - e * Q_CNT;
    const float* pbase = proto + (size_t)e * (W_CNT * C_CNT * N_CNT);
    const float* qbase = query + ((size_t)e * Q_CNT + q) * (C_CNT * N_CNT);
    unsigned char* lds = (unsigned char*)&smf;
    if (t < 320) smf.ns[t] = 0.f;
    if (t < 208) {
        if (t < 88) *reinterpret_cast<f32x4*>(smf.A + 245 * 128 + t * 16) = (f32x4){0.f,0.f,0.f,0.f};
        else        *reinterpret_cast<f32x4*>(smf.B + 49 * 128 + (t - 88) * 16) = (f32x4){0.f,0.f,0.f,0.f};
    }
    const int nslot5 = (t < 304);
    const float* gp[5];
    int offidx[5];
    #pragma unroll
    for (int i = 0; i < 5; ++i) {
        gp[i] = pbase; offidx[i] = 0;
        if (i < 4 || nslot5) {
            const int s = t + i * 512;
            if (s < 1960) {
                const int kb = s / 245, nw = s - kb * 245;
                const int w = nw / 49, n = nw - w * 49;
                gp[i] = pbase + ((size_t)w * C_CNT + kb * 8) * N_CNT + n;
                offidx[i] = (nw * 128 + ((kb ^ (nw & 7)) << 4)) | (nw << 16);
            } else {
                const int s2 = s - 1960;
                const int kb = s2 / 49, mq = s2 - kb * 49;
                gp[i] = qbase + (size_t)(kb * 8) * N_CNT + mq;
                offidx[i] = (32768 + mq * 128 + ((kb ^ (mq & 7)) << 4)) | ((256 + mq) << 16);
            }
        }
    }
    float v[5][8];
    float ss[5] = {0.f,0.f,0.f,0.f,0.f};
    #pragma unroll
    for (int i = 0; i < 4; ++i)
        #pragma unroll
        for (int j = 0; j < 8; ++j) v[i][j] = gp[i][(size_t)j * N_CNT];
    if (nslot5)
        #pragma unroll
        for (int j = 0; j < 8; ++j) v[4][j] = gp[4][(size_t)j * N_CNT];
    f32x4 acc[2][4];
    #pragma unroll
    for (int i = 0; i < 2; ++i)
        #pragma unroll
        for (int j = 0; j < 4; ++j) acc[i][j] = (f32x4){0.f,0.f,0.f,0.f};
    const int wv = t >> 6, ln = t & 63, lrow = ln & 15, lk = ln >> 4;
    for (int kc = 0; kc < 10; ++kc) {
        #pragma unroll
        for (int i = 0; i < 5; ++i) {
            if (i < 4 || nslot5) {
                bf16x8 pk; float s8 = 0.f;
                #pragma unroll
                for (int j = 0; j < 8; ++j) { const float f = v[i][j]; s8 += f*f; pk[j] = f2bf(f); }
                ss[i] += s8;
                *reinterpret_cast<bf16x8*>(lds + (offidx[i] & 0xFFFF)) = pk;
            }
        }
        __syncthreads();
        if (kc < 9) {
            #pragma unroll
            for (int i = 0; i < 4; ++i) {
                gp[i] += 64 * N_CNT;
                #pragma unroll
                for (int j = 0; j < 8; ++j) v[i][j] = gp[i][(size_t)j * N_CNT];
            }
            if (nslot5) {
                gp[4] += 64 * N_CNT;
                #pragma unroll
                for (int j = 0; j < 8; ++j) v[4][j] = gp[4][(size_t)j * N_CNT];
            }
        }
        #pragma unroll
        for (int ks = 0; ks < 2; ++ks) {
            bf16x8 af[2], bfr[4];
            #pragma unroll
            for (int i = 0; i < 2; ++i) {
                const int row = (wv * 2 + i) * 16 + lrow;
                const int gr = (ks * 4 + lk) ^ (row & 7);
                af[i] = *reinterpret_cast<const bf16x8*>(lds + row * 128 + gr * 16);
            }
            #pragma unroll
            for (int j = 0; j < 4; ++j) {
                const int mq = j * 16 + lrow;
                const int gr = (ks * 4 + lk) ^ (mq & 7);
                bfr[j] = *reinterpret_cast<const bf16x8*>(lds + 32768 + mq * 128 + gr * 16);
            }
            #pragma unroll
            for (int i = 0; i < 2; ++i)
                #pragma unroll
                for (int j = 0; j < 4; ++j)
                    acc[i][j] = __builtin_amdgcn_mfma_f32_16x16x32_bf16(af[i], bfr[j], acc[i][j], 0, 0, 0);
        }
        __syncthreads();
    }
    #pragma unroll
    for (int i = 0; i < 5; ++i)
        if (i < 4 || nslot5) atomicAdd(&smf.ns[offidx[i] >> 16], ss[i]);
    __syncthreads();
    float nq[4];
    #pragma unroll
    for (int j = 0; j < 4; ++j) {
        const int mq = j * 16 + lrow;
        nq[j] = (mq < N_CNT) ? sqrtf(smf.ns[256 + mq]) : 1.f;
    }
    float* obase = out + (size_t)(e * Q_CNT + q) * (W_CNT * N_CNT * N_CNT);
    #pragma unroll
    for (int i = 0; i < 2; ++i) {
        #pragma unroll
        for (int rr = 0; rr < 4; ++rr) {
            const int nw = (wv * 2 + i) * 16 + lk * 4 + rr;
            if (nw < W_CNT * N_CNT) {
                const int w = nw / 49, n = nw - w * 49;
                const float np_ = sqrtf(smf.ns[nw]);
                float* orow = obase + ((size_t)w * N_CNT + n) * N_CNT;
                #pragma unroll
                for (int j = 0; j < 4; ++j) {
                    const int mq = j * 16 + lrow;
                    if (mq < N_CNT) orow[mq] = acc[i][j][rr] / (np_ * nq[j] + 1e-8f);
                }
            }
        }
    }
}

extern "C" void kernel_launch(void* const* d_in, const int* in_sizes, int n_in,
                              void* d_out, int out_size, void* d_ws, size_t ws_size,
                              hipStream_t stream)
{
    const float* proto = (const float*)d_in[0];
    const float* query = (const float*)d_in[1];
    float* out = (float*)d_out;

    if (ws_size < WS1) {
        hipLaunchKernelGGL(sim_fallback_kernel, dim3(E_CNT * Q_CNT), dim3(512), 0, stream,
                           proto, query, out);
        return;
    }

    unsigned char* aimg = (unsigned char*)d_ws;
    float* pn_part = (float*)((unsigned char*)d_ws + PN_OFF);

    if (ws_size >= WS2) {
        unsigned char* bimg = (unsigned char*)d_ws + BIMG_OFF;
        float* qn_part = (float*)((unsigned char*)d_ws + QN_OFF);
        hipLaunchKernelGGL(prep_combined_kernel, dim3(2480), dim3(256), 0, stream,
                           proto, query, aimg, pn_part, bimg, qn_part);
        hipLaunchKernelGGL(gemm2_kernel, dim3(E_CNT * Q_CNT), dim3(512), 0, stream,
                           aimg, bimg, pn_part, qn_part, out);
    } else {
        hipLaunchKernelGGL(prep_a_kernel, dim3(E_CNT * 10), dim3(256), 0, stream,
                           proto, aimg, pn_part);
        hipLaunchKernelGGL(gemm_t1_kernel, dim3(E_CNT * Q_CNT), dim3(256), 0, stream,
                           query, aimg, pn_part, out);
    }
}

// Round 9
// 38.756 us; speedup vs baseline: 2.0941x; 1.4617x over previous
//
#include <hip/hip_runtime.h>
#include <hip/hip_bf16.h>

// SimilarityLayer: out[e,q,w,n,m] = <p[e,w,:,n], q[e,q,:,m]> / (|p||q| + 1e-8)
// E=8 W=5 C=640 N=49 Q=75.
// R9: no B-image. prep_a -> fragment-ordered bf16 A image (2.6 MB, L2-hot).
//     gemm3: 1200 blocks (e,q,M-half), 256 thr / 4 waves x (32 rows x 64 cols).
//     Per Kc=32 chunk: B convert staged ONCE per block via LDS (each thread = one
//     fragment granule: 8 fp32 loads -> cvt -> one linear 16B ds_write),
//     A-fragments direct from aimg. 3-buffer B-LDS + 3-buffer A-regs, loads
//     2 chunks ahead, ONE barrier/chunk, fully unrolled (static %3 indices).
//     4 blocks/CU co-resident so other gangs fill barrier stalls.

#define E_CNT 8
#define W_CNT 5
#define C_CNT 640
#define N_CNT 49
#define Q_CNT 75
#define MROWS 245                    // W*N
#define NC32 20                      // K chunks of 32
#define AFRAG_CH 16384               // per (e,chunk): 16 row-tiles x 64 lanes x 16B
#define AIMG_E (NC32 * AFRAG_CH)     // 327,680 B per e
#define AIMG_SIZE (E_CNT * AIMG_E)   // 2,621,440
#define PN_OFF AIMG_SIZE
#define PN_BYTES (E_CNT * 10 * MROWS * 4)
#define WS1 ((size_t)(PN_OFF + PN_BYTES))

typedef __attribute__((ext_vector_type(8))) short bf16x8;
typedef __attribute__((ext_vector_type(4))) float f32x4;

static __device__ __forceinline__ short f2bf(float f) {
    __hip_bfloat16 h = __float2bfloat16(f);
    return *reinterpret_cast<short*>(&h);
}

// ---------------- prep_a: proto -> fragment-ordered bf16 A image + partials --
// A[nw][k=c64*64+kb*8+j] -> chunk c32=c64*2+(kb>>2), lane ((kb&3)<<4)|(nw&15),
// byte ((nw>>4)*64 + lane)*16 + j*2.
__global__ __launch_bounds__(256, 4)
void prep_a_kernel(const float* __restrict__ proto,
                   unsigned char* __restrict__ aimg,
                   float* __restrict__ pn_part)
{
    __shared__ float pns[MROWS];
    const int b = blockIdx.x;            // 80 = e*10 + c64
    const int e = b / 10, c64 = b % 10;
    const float* pbase = proto + (size_t)e * (W_CNT * C_CNT * N_CNT);
    unsigned char* ebase = aimg + (size_t)e * AIMG_E;
    const int t = threadIdx.x;
    if (t < MROWS) pns[t] = 0.f;
    __syncthreads();

    #pragma unroll
    for (int i = 0; i < 8; ++i) {
        const int s = t + i * 256;       // slot = kb*245 + nw, kb in [0,8)
        int nw, kb;
        bf16x8 pk;
        if (s < 8 * MROWS) {
            kb = s / MROWS;
            nw = s - kb * MROWS;
            const int w = nw / N_CNT, n = nw - w * N_CNT;
            const float* g = pbase + ((size_t)(w * C_CNT + c64 * 64 + kb * 8)) * N_CNT + n;
            float ss = 0.f;
            #pragma unroll
            for (int j = 0; j < 8; ++j) {
                const float f = g[(size_t)j * N_CNT];
                ss += f * f;
                pk[j] = f2bf(f);
            }
            atomicAdd(&pns[nw], ss);
        } else {
            const int x = s - 8 * MROWS; // zero-pad rows 245..255
            nw = MROWS + (x >> 3);
            kb = x & 7;
            pk = (bf16x8){0, 0, 0, 0, 0, 0, 0, 0};
        }
        const int c32 = c64 * 2 + (kb >> 2);
        const int ln2 = ((kb & 3) << 4) | (nw & 15);
        *reinterpret_cast<bf16x8*>(
            ebase + (size_t)c32 * AFRAG_CH + (size_t)((nw >> 4) * 64 + ln2) * 16) = pk;
    }
    __syncthreads();
    if (t < MROWS) pn_part[(size_t)(e * 10 + c64) * MROWS + t] = pns[t];
}

// ---------------- gemm3: fused B-convert (LDS-shared) + MFMA -----------------
__global__ __launch_bounds__(256, 4)
void gemm3_kernel(const float* __restrict__ query,
                  const unsigned char* __restrict__ aimg,
                  const float* __restrict__ pn_part,
                  float* __restrict__ out)
{
    __shared__ __align__(16) unsigned char Bbuf[3 * 4096];  // 3 x (4 fj x 64 lanes x 16B)
    __shared__ float qn[64];
    __shared__ float pnl[128];

    const int b = blockIdx.x;            // 1200
    const int e = b & 7;                 // same e -> same XCD -> aimg L2-hot
    const int mh = (b >> 3) & 1;         // M-half: rows [mh*128, +128)
    const int q = b >> 4;                // 0..74
    const int eq = e * Q_CNT + q;
    const int t = threadIdx.x;
    const int wv = t >> 6, ln = t & 63;
    const int lrow = ln & 15, lk = ln >> 4;

    const float* __restrict__ qsl = query + (size_t)eq * (C_CNT * N_CNT);

    // B staging: thread t owns fragment granule (fj = wv, lane = ln):
    //   col = wv*16 + (ln&15), k-group = ln>>4 (8 consecutive k)
    const int scol = wv * 16 + lrow;
    const int scolc = (scol < N_CNT) ? scol : (N_CNT - 1);  // clamp; cols>=49 unused
    const float* __restrict__ sbase = qsl + (size_t)(lk * 8) * N_CNT + scolc;
    const int swoff = wv * 1024 + ln * 16;   // linear dest within one 4K buffer

    // A fragments: this wave's 2 row-tiles
    const int rt0 = mh * 8 + wv * 2;
    const unsigned char* __restrict__ abase =
        aimg + (size_t)e * AIMG_E + (size_t)(rt0 * 64 + ln) * 16;

    // p-norms for this block's 128 rows
    if (t < 128) {
        const int row = mh * 128 + t;
        float s = 0.f;
        if (row < MROWS) {
            #pragma unroll
            for (int cc = 0; cc < 10; ++cc)
                s += pn_part[(size_t)(e * 10 + cc) * MROWS + row];
        }
        pnl[t] = sqrtf(s);
    }

    float vB[2][8];                      // raw fp32 B, 2-deep (chunk parity)
    bf16x8 afr[3][2];                    // A frags, 3-deep
    f32x4 acc[2][4];
    #pragma unroll
    for (int i = 0; i < 2; ++i)
        #pragma unroll
        for (int j = 0; j < 4; ++j) acc[i][j] = (f32x4){0.f, 0.f, 0.f, 0.f};
    float ssq = 0.f;

#define G3_BISSUE(c, s_) do {                                                   \
    _Pragma("unroll")                                                           \
    for (int j_ = 0; j_ < 8; ++j_)                                              \
        vB[s_][j_] = sbase[(size_t)((c) * 32 + j_) * N_CNT];                    \
} while (0)

#define G3_AISSUE(c, s_) do {                                                   \
    _Pragma("unroll")                                                           \
    for (int fi_ = 0; fi_ < 2; ++fi_)                                           \
        afr[s_][fi_] = *reinterpret_cast<const bf16x8*>(                        \
            abase + (size_t)(c) * AFRAG_CH + fi_ * 1024);                       \
} while (0)

#define G3_CVTW(s_, buf) do {                                                   \
    bf16x8 pk_;                                                                 \
    _Pragma("unroll")                                                           \
    for (int j_ = 0; j_ < 8; ++j_) {                                            \
        const float f_ = vB[s_][j_]; ssq += f_ * f_; pk_[j_] = f2bf(f_);        \
    }                                                                           \
    *reinterpret_cast<bf16x8*>(Bbuf + (buf) * 4096 + swoff) = pk_;              \
} while (0)

    // prologue: chunks 0,1 in flight; chunk 0 staged to LDS
    G3_BISSUE(0, 0);
    G3_AISSUE(0, 0);
    G3_BISSUE(1, 1);
    G3_AISSUE(1, 1);
    G3_CVTW(0, 0);
    __syncthreads();

    #pragma unroll
    for (int c = 0; c < NC32; ++c) {     // fully unrolled: %3 indices static
        if (c + 2 < NC32) {
            G3_BISSUE(c + 2, c & 1);     // (c+2)&1 == c&1; vB[c&1] was converted at iter c-1
            G3_AISSUE(c + 2, (c + 2) % 3);
        }
        // MFMA on chunk c
        {
            const unsigned char* bb = Bbuf + (c % 3) * 4096;
            bf16x8 bfr[4];
            #pragma unroll
            for (int fj = 0; fj < 4; ++fj)
                bfr[fj] = *reinterpret_cast<const bf16x8*>(bb + fj * 1024 + ln * 16);
            #pragma unroll
            for (int fi = 0; fi < 2; ++fi)
                #pragma unroll
                for (int fj = 0; fj < 4; ++fj)
                    acc[fi][fj] = __builtin_amdgcn_mfma_f32_16x16x32_bf16(
                        afr[c % 3][fi], bfr[fj], acc[fi][fj], 0, 0, 0);
        }
        if (c + 1 < NC32)
            G3_CVTW((c + 1) & 1, (c + 1) % 3);   // stage chunk c+1 (loaded >=1 iter ago)
        __syncthreads();
    }

    // ---- q-norms: reduce ssq over the 4 k-groups of each column ----
    {
        float s = ssq;
        s += __shfl_xor(s, 16);
        s += __shfl_xor(s, 32);
        if (lk == 0) qn[wv * 16 + lrow] = s;     // col = wv*16 + lrow
    }
    __syncthreads();

    // ---- epilogue: rows mh*128 + wv*32 + fi*16 + lk*4 + rr ; cols fj*16+lrow ----
    float nq4[4];
    #pragma unroll
    for (int fj = 0; fj < 4; ++fj) {
        const int m = fj * 16 + lrow;
        nq4[fj] = (m < N_CNT) ? sqrtf(qn[m]) : 1.f;
    }
    float* __restrict__ osl = out + (size_t)eq * (W_CNT * N_CNT * N_CNT);
    #pragma unroll
    for (int fi = 0; fi < 2; ++fi) {
        #pragma unroll
        for (int rr = 0; rr < 4; ++rr) {
            const int lr = wv * 32 + fi * 16 + lk * 4 + rr;  // row within half
            const int row = mh * 128 + lr;
            if (row < MROWS) {
                const float np_ = pnl[lr];
                #pragma unroll
                for (int fj = 0; fj < 4; ++fj) {
                    const int m = fj * 16 + lrow;
                    if (m < N_CNT) {
                        const float den = np_ * nq4[fj] + 1e-8f;
                        osl[row * N_CNT + m] = acc[fi][fj][rr] * __builtin_amdgcn_rcpf(den);
                    }
                }
            }
        }
    }
#undef G3_BISSUE
#undef G3_AISSUE
#undef G3_CVTW
}

// ---------------- tier-0 fallback (R2 kernel, no ws) -------------------------
struct SMemFB {
    unsigned char A[256 * 128];
    unsigned char B[64 * 128];
    float ns[320];
};

__global__ __launch_bounds__(512, 4)
void sim_fallback_kernel(const float* __restrict__ proto,
                         const float* __restrict__ query,
                         float* __restrict__ out)
{
    __shared__ SMemFB smf;
    const int t = threadIdx.x;
    const int e = blockIdx.x / Q_CNT;
    const int q = blockIdx.x - e * Q_CNT;
    const float* pbase = proto + (size_t)e * (W_CNT * C_CNT * N_CNT);
    const float* qbase = query + ((size_t)e * Q_CNT + q) * (C_CNT * N_CNT);
    unsigned char* lds = (unsigned char*)&smf;
    if (t < 320) smf.ns[t] = 0.f;
    if (t < 208) {
        if (t < 88) *reinterpret_cast<f32x4*>(smf.A + 245 * 128 + t * 16) = (f32x4){0.f,0.f,0.f,0.f};
        else        *reinterpret_cast<f32x4*>(smf.B + 49 * 128 + (t - 88) * 16) = (f32x4){0.f,0.f,0.f,0.f};
    }
    const int nslot5 = (t < 304);
    const float* gp[5];
    int offidx[5];
    #pragma unroll
    for (int i = 0; i < 5; ++i) {
        gp[i] = pbase; offidx[i] = 0;
        if (i < 4 || nslot5) {
            const int s = t + i * 512;
            if (s < 1960) {
                const int kb = s / 245, nw = s - kb * 245;
                const int w = nw / 49, n = nw - w * 49;
                gp[i] = pbase + ((size_t)w * C_CNT + kb * 8) * N_CNT + n;
                offidx[i] = (nw * 128 + ((kb ^ (nw & 7)) << 4)) | (nw << 16);
            } else {
                const int s2 = s - 1960;
                const int kb = s2 / 49, mq = s2 - kb * 49;
                gp[i] = qbase + (size_t)(kb * 8) * N_CNT + mq;
                offidx[i] = (32768 + mq * 128 + ((kb ^ (mq & 7)) << 4)) | ((256 + mq) << 16);
            }
        }
    }
    float v[5][8];
    float ss[5] = {0.f,0.f,0.f,0.f,0.f};
    #pragma unroll
    for (int i = 0; i < 4; ++i)
        #pragma unroll
        for (int j = 0; j < 8; ++j) v[i][j] = gp[i][(size_t)j * N_CNT];
    if (nslot5)
        #pragma unroll
        for (int j = 0; j < 8; ++j) v[4][j] = gp[4][(size_t)j * N_CNT];
    f32x4 acc[2][4];
    #pragma unroll
    for (int i = 0; i < 2; ++i)
        #pragma unroll
        for (int j = 0; j < 4; ++j) acc[i][j] = (f32x4){0.f,0.f,0.f,0.f};
    const int wv = t >> 6, ln = t & 63, lrow = ln & 15, lk = ln >> 4;
    for (int kc = 0; kc < 10; ++kc) {
        #pragma unroll
        for (int i = 0; i < 5; ++i) {
            if (i < 4 || nslot5) {
                bf16x8 pk; float s8 = 0.f;
                #pragma unroll
                for (int j = 0; j < 8; ++j) { const float f = v[i][j]; s8 += f*f; pk[j] = f2bf(f); }
                ss[i] += s8;
                *reinterpret_cast<bf16x8*>(lds + (offidx[i] & 0xFFFF)) = pk;
            }
        }
        __syncthreads();
        if (kc < 9) {
            #pragma unroll
            for (int i = 0; i < 4; ++i) {
                gp[i] += 64 * N_CNT;
                #pragma unroll
                for (int j = 0; j < 8; ++j) v[i][j] = gp[i][(size_t)j * N_CNT];
            }
            if (nslot5) {
                gp[4] += 64 * N_CNT;
                #pragma unroll
                for (int j = 0; j < 8; ++j) v[4][j] = gp[4][(size_t)j * N_CNT];
            }
        }
        #pragma unroll
        for (int ks = 0; ks < 2; ++ks) {
            bf16x8 af[2], bfr[4];
            #pragma unroll
            for (int i = 0; i < 2; ++i) {
                const int row = (wv * 2 + i) * 16 + lrow;
                const int gr = (ks * 4 + lk) ^ (row & 7);
                af[i] = *reinterpret_cast<const bf16x8*>(lds + row * 128 + gr * 16);
            }
            #pragma unroll
            for (int j = 0; j < 4; ++j) {
                const int mq = j * 16 + lrow;
                const int gr = (ks * 4 + lk) ^ (mq & 7);
                bfr[j] = *reinterpret_cast<const bf16x8*>(lds + 32768 + mq * 128 + gr * 16);
            }
            #pragma unroll
            for (int i = 0; i < 2; ++i)
                #pragma unroll
                for (int j = 0; j < 4; ++j)
                    acc[i][j] = __builtin_amdgcn_mfma_f32_16x16x32_bf16(af[i], bfr[j], acc[i][j], 0, 0, 0);
        }
        __syncthreads();
    }
    #pragma unroll
    for (int i = 0; i < 5; ++i)
        if (i < 4 || nslot5) atomicAdd(&smf.ns[offidx[i] >> 16], ss[i]);
    __syncthreads();
    float nq[4];
    #pragma unroll
    for (int j = 0; j < 4; ++j) {
        const int mq = j * 16 + lrow;
        nq[j] = (mq < N_CNT) ? sqrtf(smf.ns[256 + mq]) : 1.f;
    }
    float* obase = out + (size_t)(e * Q_CNT + q) * (W_CNT * N_CNT * N_CNT);
    #pragma unroll
    for (int i = 0; i < 2; ++i) {
        #pragma unroll
        for (int rr = 0; rr < 4; ++rr) {
            const int nw = (wv * 2 + i) * 16 + lk * 4 + rr;
            if (nw < W_CNT * N_CNT) {
                const int w = nw / 49, n = nw - w * 49;
                const float np_ = sqrtf(smf.ns[nw]);
                float* orow = obase + ((size_t)w * N_CNT + n) * N_CNT;
                #pragma unroll
                for (int j = 0; j < 4; ++j) {
                    const int mq = j * 16 + lrow;
                    if (mq < N_CNT) orow[mq] = acc[i][j][rr] / (np_ * nq[j] + 1e-8f);
                }
            }
        }
    }
}

extern "C" void kernel_launch(void* const* d_in, const int* in_sizes, int n_in,
                              void* d_out, int out_size, void* d_ws, size_t ws_size,
                              hipStream_t stream)
{
    const float* proto = (const float*)d_in[0];
    const float* query = (const float*)d_in[1];
    float* out = (float*)d_out;

    if (ws_size < WS1) {
        hipLaunchKernelGGL(sim_fallback_kernel, dim3(E_CNT * Q_CNT), dim3(512), 0, stream,
                           proto, query, out);
        return;
    }

    unsigned char* aimg = (unsigned char*)d_ws;
    float* pn_part = (float*)((unsigned char*)d_ws + PN_OFF);

    hipLaunchKernelGGL(prep_a_kernel, dim3(E_CNT * 10), dim3(256), 0, stream,
                       proto, aimg, pn_part);
    hipLaunchKernelGGL(gemm3_kernel, dim3(E_CNT * Q_CNT * 2), dim3(256), 0, stream,
                       query, aimg, pn_part, out);
}